// Round 2
// baseline (1918.629 us; speedup 1.0000x reference)
//
#include <hip/hip_runtime.h>

// ---------------- problem constants ----------------
#define H_DIM 256
#define E_NUM 524288
#define NN    32768          // B*N nodes
#define K2    512            // 2H
#define K2S   520            // LDS row stride (u16) kernel k_nodes
#define SAS   264            // LDS row stride (u16) for 256-wide A tiles
#define XS    264            // fp32/u16 intermediate row stride in k_nodes

typedef unsigned short u16;
typedef unsigned int   u32;
typedef __attribute__((ext_vector_type(8))) short s16x8;
typedef __attribute__((ext_vector_type(4))) float f32x4;
typedef __attribute__((ext_vector_type(4))) unsigned short u16x4;

__device__ __forceinline__ u16 f2b(float x) {
    u32 u = __float_as_uint(x);
    u32 r = (u + 0x7FFFu + ((u >> 16) & 1u)) >> 16;   // RNE; inputs finite
    return (u16)r;
}
__device__ __forceinline__ float b2f(u16 v) {
    u32 u = ((u32)v) << 16;
    return __uint_as_float(u);
}

// ---------------- weight prep: build bf16 transposed weights ----------------
// WpqT[c][k] c<512,k<256 ; W2T[c][k] 256x256 ; U1T[c][k] c<256,k<512 ; U2T 256x256
__global__ __launch_bounds__(256) void k_prep_w(
    const float* __restrict__ W1, const float* __restrict__ W2,
    const float* __restrict__ U1, const float* __restrict__ U2,
    u16* __restrict__ WpqT, u16* __restrict__ W2T,
    u16* __restrict__ U1T, u16* __restrict__ U2T) {
    int idx = blockIdx.x * 256 + threadIdx.x;
    if (idx < 131072) {                       // WpqT
        int c = idx >> 8, k = idx & 255;
        float v = (c < 256) ? W1[k * 256 + c] : W1[(256 + k) * 256 + (c - 256)];
        WpqT[idx] = f2b(v);
    } else if (idx < 196608) {                // W2T
        int i = idx - 131072; int c = i >> 8, k = i & 255;
        W2T[i] = f2b(W2[k * 256 + c]);
    } else if (idx < 327680) {                // U1T
        int i = idx - 196608; int c = i >> 9, k = i & 511;
        U1T[i] = f2b(U1[(size_t)k * 256 + c]);
    } else if (idx < 393216) {                // U2T
        int i = idx - 327680; int c = i >> 8, k = i & 255;
        U2T[i] = f2b(U2[k * 256 + c]);
    }
}

// ---------------- node GEMM: [P|Q] = h @ [W1a|W1b]  (bf16 out, NN x 512) ----------------
// grid = (NN/64)*2, 256 thr. Block: 64 rows x 256 cols (half q of the 512).
__global__ __launch_bounds__(256, 2) void k_gemm_pq(
    const float* __restrict__ h, const u16* __restrict__ WpqT,
    u16* __restrict__ PQ) {
    __shared__ __align__(16) u16 sA[64 * SAS];
    const int t = threadIdx.x;
    const int rowTile = blockIdx.x >> 1, q = blockIdx.x & 1;
    const int n0 = rowTile * 64;
    {   // stage h tile (fp32 -> bf16)
        const int r = t >> 2, g = t & 3;
        const float* hrow = h + (size_t)(n0 + r) * 256;
        u16* rowp = sA + r * SAS;
#pragma unroll
        for (int j = 0; j < 8; ++j) {
            const int c = g + 4 * j;          // 0..31 chunks of 8 floats
            float4 v0 = *reinterpret_cast<const float4*>(hrow + c * 8);
            float4 v1 = *reinterpret_cast<const float4*>(hrow + c * 8 + 4);
            s16x8 o;
            o[0] = (short)f2b(v0.x); o[1] = (short)f2b(v0.y);
            o[2] = (short)f2b(v0.z); o[3] = (short)f2b(v0.w);
            o[4] = (short)f2b(v1.x); o[5] = (short)f2b(v1.y);
            o[6] = (short)f2b(v1.z); o[7] = (short)f2b(v1.w);
            *reinterpret_cast<s16x8*>(rowp + c * 8) = o;
        }
    }
    __syncthreads();
    const int lane = t & 63, wv = t >> 6;
    const int l15 = lane & 15, l4 = lane >> 4;
    const int colBase = wv * 64 + l15;
    const f32x4 z4 = {0.f, 0.f, 0.f, 0.f};
    f32x4 acc[4][4];
#pragma unroll
    for (int m = 0; m < 4; ++m)
#pragma unroll
        for (int n = 0; n < 4; ++n) acc[m][n] = z4;
    {
        const u16* Bb = WpqT + (size_t)(q * 256 + colBase) * 256 + l4 * 8;
        for (int kk = 0; kk < 8; ++kk) {
            s16x8 a[4], b[4];
#pragma unroll
            for (int m = 0; m < 4; ++m)
                a[m] = *reinterpret_cast<const s16x8*>(sA + (m * 16 + l15) * SAS + kk * 32 + l4 * 8);
#pragma unroll
            for (int n = 0; n < 4; ++n)
                b[n] = *reinterpret_cast<const s16x8*>(Bb + (size_t)n * 16 * 256 + kk * 32);
#pragma unroll
            for (int m = 0; m < 4; ++m)
#pragma unroll
                for (int n = 0; n < 4; ++n)
                    acc[m][n] = __builtin_amdgcn_mfma_f32_16x16x32_bf16(a[m], b[n], acc[m][n], 0, 0, 0);
        }
    }
#pragma unroll
    for (int m = 0; m < 4; ++m)
#pragma unroll
        for (int j = 0; j < 4; ++j) {
            const int row = n0 + m * 16 + l4 * 4 + j;
            u16* op = PQ + (size_t)row * 512 + q * 256 + colBase;
#pragma unroll
            for (int n = 0; n < 4; ++n) op[n * 16] = f2b(acc[m][n][j]);
        }
}

// ---------------- edge pass: X = P[src]+Q[dst]+ea@W1c+b1 ; scatter-add silu(X) ----------------
// grid = 2048 blocks x 4 waves; wave handles 64 contiguous edges; lane owns 4 cols.
__global__ __launch_bounds__(256, 4) void k_edge(
    const u16* __restrict__ PQ, const int* __restrict__ eidx,
    const float* __restrict__ ea, const float* __restrict__ W1,
    const float* __restrict__ b1,
    float* __restrict__ S, float* __restrict__ deg) {
    const int t = threadIdx.x;
    const int lane = t & 63, wv = t >> 6;
    const int c0 = lane * 4;
    // W1c (rows 512..527 of W1) held in registers: Wr[k] = W1c[k][c0..c0+3]
    float4 Wr[16];
#pragma unroll
    for (int k = 0; k < 16; ++k)
        Wr[k] = *reinterpret_cast<const float4*>(W1 + (size_t)(512 + k) * 256 + c0);
    const float4 b1v = *reinterpret_cast<const float4*>(b1 + c0);

    const int wid = blockIdx.x * 4 + wv;       // 0..8191
    int e = wid * 64;
    int s = eidx[e], d = eidx[E_NUM + e];
    for (int i = 0; i < 64; ++i) {
        // issue gathers for current edge ASAP
        const u16x4 pv = *reinterpret_cast<const u16x4*>(PQ + (size_t)s * 512 + c0);
        const u16x4 qv = *reinterpret_cast<const u16x4*>(PQ + (size_t)d * 512 + 256 + c0);
        // prefetch next edge's indices
        int sn = 0, dn = 0;
        if (i < 63) { sn = eidx[e + 1]; dn = eidx[E_NUM + e + 1]; }
        // edge_attr (uniform broadcast, L2)
        const float4* eap = reinterpret_cast<const float4*>(ea + (size_t)e * 16);
        const float4 e0 = eap[0], e1 = eap[1], e2 = eap[2], e3 = eap[3];
        float4 x = b1v;
        x.x += e0.x * Wr[0].x; x.y += e0.x * Wr[0].y; x.z += e0.x * Wr[0].z; x.w += e0.x * Wr[0].w;
        x.x += e0.y * Wr[1].x; x.y += e0.y * Wr[1].y; x.z += e0.y * Wr[1].z; x.w += e0.y * Wr[1].w;
        x.x += e0.z * Wr[2].x; x.y += e0.z * Wr[2].y; x.z += e0.z * Wr[2].z; x.w += e0.z * Wr[2].w;
        x.x += e0.w * Wr[3].x; x.y += e0.w * Wr[3].y; x.z += e0.w * Wr[3].z; x.w += e0.w * Wr[3].w;
        x.x += e1.x * Wr[4].x; x.y += e1.x * Wr[4].y; x.z += e1.x * Wr[4].z; x.w += e1.x * Wr[4].w;
        x.x += e1.y * Wr[5].x; x.y += e1.y * Wr[5].y; x.z += e1.y * Wr[5].z; x.w += e1.y * Wr[5].w;
        x.x += e1.z * Wr[6].x; x.y += e1.z * Wr[6].y; x.z += e1.z * Wr[6].z; x.w += e1.z * Wr[6].w;
        x.x += e1.w * Wr[7].x; x.y += e1.w * Wr[7].y; x.z += e1.w * Wr[7].z; x.w += e1.w * Wr[7].w;
        x.x += e2.x * Wr[8].x; x.y += e2.x * Wr[8].y; x.z += e2.x * Wr[8].z; x.w += e2.x * Wr[8].w;
        x.x += e2.y * Wr[9].x; x.y += e2.y * Wr[9].y; x.z += e2.y * Wr[9].z; x.w += e2.y * Wr[9].w;
        x.x += e2.z * Wr[10].x; x.y += e2.z * Wr[10].y; x.z += e2.z * Wr[10].z; x.w += e2.z * Wr[10].w;
        x.x += e2.w * Wr[11].x; x.y += e2.w * Wr[11].y; x.z += e2.w * Wr[11].z; x.w += e2.w * Wr[11].w;
        x.x += e3.x * Wr[12].x; x.y += e3.x * Wr[12].y; x.z += e3.x * Wr[12].z; x.w += e3.x * Wr[12].w;
        x.x += e3.y * Wr[13].x; x.y += e3.y * Wr[13].y; x.z += e3.y * Wr[13].z; x.w += e3.y * Wr[13].w;
        x.x += e3.z * Wr[14].x; x.y += e3.z * Wr[14].y; x.z += e3.z * Wr[14].z; x.w += e3.z * Wr[14].w;
        x.x += e3.w * Wr[15].x; x.y += e3.w * Wr[15].y; x.z += e3.w * Wr[15].z; x.w += e3.w * Wr[15].w;
        // add gathered P,Q
        x.x += b2f(pv.x) + b2f(qv.x);
        x.y += b2f(pv.y) + b2f(qv.y);
        x.z += b2f(pv.z) + b2f(qv.z);
        x.w += b2f(pv.w) + b2f(qv.w);
        // silu
        float4 y;
        y.x = x.x / (1.f + __expf(-x.x));
        y.y = x.y / (1.f + __expf(-x.y));
        y.z = x.z / (1.f + __expf(-x.z));
        y.w = x.w / (1.f + __expf(-x.w));
        // scatter
        float* Sp = S + (size_t)d * 256 + c0;
        atomicAdd(Sp + 0, y.x);
        atomicAdd(Sp + 1, y.y);
        atomicAdd(Sp + 2, y.z);
        atomicAdd(Sp + 3, y.w);
        if (lane == 0) atomicAdd(deg + d, 1.0f);
        s = sn; d = dn; ++e;
    }
}

// ---------------- node GEMM: aggr = S @ W2 + deg*b2  (bf16 out, NN x 256) ----------------
__global__ __launch_bounds__(256, 2) void k_gemm_s(
    const float* __restrict__ S, const u16* __restrict__ W2T,
    const float* __restrict__ deg, const float* __restrict__ b2,
    u16* __restrict__ aggrb) {
    __shared__ __align__(16) u16 sA[64 * SAS];
    const int t = threadIdx.x;
    const int n0 = blockIdx.x * 64;
    {   // stage S tile (fp32 -> bf16)
        const int r = t >> 2, g = t & 3;
        const float* srow = S + (size_t)(n0 + r) * 256;
        u16* rowp = sA + r * SAS;
#pragma unroll
        for (int j = 0; j < 8; ++j) {
            const int c = g + 4 * j;
            float4 v0 = *reinterpret_cast<const float4*>(srow + c * 8);
            float4 v1 = *reinterpret_cast<const float4*>(srow + c * 8 + 4);
            s16x8 o;
            o[0] = (short)f2b(v0.x); o[1] = (short)f2b(v0.y);
            o[2] = (short)f2b(v0.z); o[3] = (short)f2b(v0.w);
            o[4] = (short)f2b(v1.x); o[5] = (short)f2b(v1.y);
            o[6] = (short)f2b(v1.z); o[7] = (short)f2b(v1.w);
            *reinterpret_cast<s16x8*>(rowp + c * 8) = o;
        }
    }
    __syncthreads();
    const int lane = t & 63, wv = t >> 6;
    const int l15 = lane & 15, l4 = lane >> 4;
    const int colBase = wv * 64 + l15;
    const f32x4 z4 = {0.f, 0.f, 0.f, 0.f};
    f32x4 acc[4][4];
#pragma unroll
    for (int m = 0; m < 4; ++m)
#pragma unroll
        for (int n = 0; n < 4; ++n) acc[m][n] = z4;
    {
        const u16* Bb = W2T + (size_t)colBase * 256 + l4 * 8;
        for (int kk = 0; kk < 8; ++kk) {
            s16x8 a[4], b[4];
#pragma unroll
            for (int m = 0; m < 4; ++m)
                a[m] = *reinterpret_cast<const s16x8*>(sA + (m * 16 + l15) * SAS + kk * 32 + l4 * 8);
#pragma unroll
            for (int n = 0; n < 4; ++n)
                b[n] = *reinterpret_cast<const s16x8*>(Bb + (size_t)n * 16 * 256 + kk * 32);
#pragma unroll
            for (int m = 0; m < 4; ++m)
#pragma unroll
                for (int n = 0; n < 4; ++n)
                    acc[m][n] = __builtin_amdgcn_mfma_f32_16x16x32_bf16(a[m], b[n], acc[m][n], 0, 0, 0);
        }
    }
    float b2v[4];
#pragma unroll
    for (int n = 0; n < 4; ++n) b2v[n] = b2[colBase + n * 16];
#pragma unroll
    for (int m = 0; m < 4; ++m)
#pragma unroll
        for (int j = 0; j < 4; ++j) {
            const int row = n0 + m * 16 + l4 * 4 + j;
            const float dv = deg[row];
            u16* op = aggrb + (size_t)row * 256 + colBase;
#pragma unroll
            for (int n = 0; n < 4; ++n) op[n * 16] = f2b(acc[m][n][j] + dv * b2v[n]);
        }
}

// ---------------- node update MLP + residual + LayerNorm + mask ----------------
__global__ __launch_bounds__(256, 2) void k_nodes(
    const float* __restrict__ h, const u16* __restrict__ aggrb,
    const u16* __restrict__ U1T, const u16* __restrict__ U2T,
    const float* __restrict__ c1, const float* __restrict__ c2,
    const float* __restrict__ gamma, const float* __restrict__ beta,
    const float* __restrict__ mask,
    float* __restrict__ out) {
    __shared__ __align__(16) char smemraw[64 * XS * 4];  // 67584 B, multi-purpose
    u16* sA = reinterpret_cast<u16*>(smemraw);           // [64][K2S] bf16
    const int t  = threadIdx.x;
    const int n0 = blockIdx.x * 64;

    {   // stage [h(bf16-converted) | aggrb]
        const int r = t >> 2, g = t & 3;
        const int node = n0 + r;
        const float* hrow = h + (size_t)node * H_DIM;
        const u16* arow = aggrb + (size_t)node * H_DIM;
        u16* rowp = sA + r * K2S;
#pragma unroll
        for (int j = 0; j < 16; ++j) {
            const int c = g + 4 * j;   // 0..63
            if (c < 32) {
                float4 v0 = *reinterpret_cast<const float4*>(hrow + c * 8);
                float4 v1 = *reinterpret_cast<const float4*>(hrow + c * 8 + 4);
                s16x8 o;
                o[0] = (short)f2b(v0.x); o[1] = (short)f2b(v0.y);
                o[2] = (short)f2b(v0.z); o[3] = (short)f2b(v0.w);
                o[4] = (short)f2b(v1.x); o[5] = (short)f2b(v1.y);
                o[6] = (short)f2b(v1.z); o[7] = (short)f2b(v1.w);
                *reinterpret_cast<s16x8*>(rowp + c * 8) = o;
            } else {
                const int cc = c - 32;
                *reinterpret_cast<s16x8*>(rowp + 256 + cc * 8) =
                    *reinterpret_cast<const s16x8*>(arow + cc * 8);
            }
        }
    }
    __syncthreads();

    const int lane = t & 63, wv = t >> 6;
    const int l15 = lane & 15, l4 = lane >> 4;
    const int colBase = wv * 64 + l15;
    const f32x4 z4 = {0.f, 0.f, 0.f, 0.f};

    f32x4 acc[4][4];
#pragma unroll
    for (int m = 0; m < 4; ++m)
#pragma unroll
        for (int n = 0; n < 4; ++n) acc[m][n] = z4;

    // ---- GEMM1b: (64 x 512) @ U1T^T ----
    {
        const u16* Bb = U1T + (size_t)colBase * K2 + l4 * 8;
        for (int kk = 0; kk < 16; ++kk) {
            s16x8 a[4], b[4];
#pragma unroll
            for (int m = 0; m < 4; ++m)
                a[m] = *reinterpret_cast<const s16x8*>(sA + (m * 16 + l15) * K2S + kk * 32 + l4 * 8);
#pragma unroll
            for (int n = 0; n < 4; ++n)
                b[n] = *reinterpret_cast<const s16x8*>(Bb + (size_t)n * 16 * K2 + kk * 32);
#pragma unroll
            for (int m = 0; m < 4; ++m)
#pragma unroll
                for (int n = 0; n < 4; ++n)
                    acc[m][n] = __builtin_amdgcn_mfma_f32_16x16x32_bf16(a[m], b[n], acc[m][n], 0, 0, 0);
        }
    }
    __syncthreads();

    // ---- epilogue 1: +c1, silu, bf16 -> sX ----
    {
        u16* sX = reinterpret_cast<u16*>(smemraw);
        float c1v[4];
#pragma unroll
        for (int n = 0; n < 4; ++n) c1v[n] = c1[colBase + n * 16];
#pragma unroll
        for (int m = 0; m < 4; ++m)
#pragma unroll
            for (int n = 0; n < 4; ++n)
#pragma unroll
                for (int j = 0; j < 4; ++j) {
                    float x = acc[m][n][j] + c1v[n];
                    float s = x / (1.f + __expf(-x));
                    sX[(m * 16 + l4 * 4 + j) * XS + colBase + n * 16] = f2b(s);
                }
    }
    __syncthreads();

    // ---- GEMM2b: (64 x 256) @ U2T^T ----
#pragma unroll
    for (int m = 0; m < 4; ++m)
#pragma unroll
        for (int n = 0; n < 4; ++n) acc[m][n] = z4;
    {
        const u16* sX = reinterpret_cast<u16*>(smemraw);
        const u16* Bb = U2T + (size_t)colBase * H_DIM + l4 * 8;
        for (int kk = 0; kk < 8; ++kk) {
            s16x8 a[4], b[4];
#pragma unroll
            for (int m = 0; m < 4; ++m)
                a[m] = *reinterpret_cast<const s16x8*>(sX + (m * 16 + l15) * XS + kk * 32 + l4 * 8);
#pragma unroll
            for (int n = 0; n < 4; ++n)
                b[n] = *reinterpret_cast<const s16x8*>(Bb + (size_t)n * 16 * H_DIM + kk * 32);
#pragma unroll
            for (int m = 0; m < 4; ++m)
#pragma unroll
                for (int n = 0; n < 4; ++n)
                    acc[m][n] = __builtin_amdgcn_mfma_f32_16x16x32_bf16(a[m], b[n], acc[m][n], 0, 0, 0);
        }
    }
    __syncthreads();   // done reading sX before overwriting as fp32

    // ---- epilogue 2: +c2 + residual -> sF (fp32) ----
    {
        float* sF = reinterpret_cast<float*>(smemraw);   // [64][XS]
        float c2v[4];
#pragma unroll
        for (int n = 0; n < 4; ++n) c2v[n] = c2[colBase + n * 16];
#pragma unroll
        for (int m = 0; m < 4; ++m)
#pragma unroll
            for (int n = 0; n < 4; ++n)
#pragma unroll
                for (int j = 0; j < 4; ++j) {
                    const int row = m * 16 + l4 * 4 + j;
                    const float hv = h[(size_t)(n0 + row) * H_DIM + colBase + n * 16];
                    sF[row * XS + colBase + n * 16] = acc[m][n][j] + c2v[n] + hv;
                }
    }
    __syncthreads();

    // ---- LayerNorm + mask + store (4 threads per row) ----
    {
        const float* sF = reinterpret_cast<const float*>(smemraw);
        const int rr = t >> 2, p = t & 3;
        const float* rowf = sF + rr * XS + p * 64;
        float s1 = 0.f, s2 = 0.f;
#pragma unroll
        for (int i = 0; i < 64; ++i) { float v = rowf[i]; s1 += v; s2 += v * v; }
        s1 += __shfl_xor(s1, 1); s1 += __shfl_xor(s1, 2);
        s2 += __shfl_xor(s2, 1); s2 += __shfl_xor(s2, 2);
        const float mu   = s1 * (1.f / 256.f);
        const float var  = s2 * (1.f / 256.f) - mu * mu;
        const float rstd = rsqrtf(var + 1e-5f);
        const int node = n0 + rr;
        const float mk = mask[node];
        float* op = out + (size_t)node * H_DIM + p * 64;
        const float* gp = gamma + p * 64;
        const float* bp = beta + p * 64;
#pragma unroll
        for (int i = 0; i < 64; i += 4) {
            float4 x  = *reinterpret_cast<const float4*>(rowf + i);
            float4 g4 = *reinterpret_cast<const float4*>(gp + i);
            float4 b4 = *reinterpret_cast<const float4*>(bp + i);
            float4 o;
            o.x = (((x.x - mu) * rstd) * g4.x + b4.x) * mk;
            o.y = (((x.y - mu) * rstd) * g4.y + b4.y) * mk;
            o.z = (((x.z - mu) * rstd) * g4.z + b4.z) * mk;
            o.w = (((x.w - mu) * rstd) * g4.w + b4.w) * mk;
            *reinterpret_cast<float4*>(op + i) = o;
        }
    }
}

// ---------------- workspace layout (bytes) ----------------
#define OFF_S      0ull                      // 32768*256*4 = 33554432
#define OFF_DEG    33554432ull               // 32768*4     = 131072
#define OFF_PQ     33685504ull               // 32768*512*2 = 33554432
#define OFF_AGGRB  67239936ull               // 32768*256*2 = 16777216
#define OFF_WPQT   84017152ull               // 512*256*2   = 262144
#define OFF_W2T    84279296ull               // 256*256*2   = 131072
#define OFF_U1T    84410368ull               // 256*512*2   = 262144
#define OFF_U2T    84672512ull               // 256*256*2   = 131072

extern "C" void kernel_launch(void* const* d_in, const int* in_sizes, int n_in,
                              void* d_out, int out_size, void* d_ws, size_t ws_size,
                              hipStream_t stream) {
    const float* h     = (const float*)d_in[0];
    const int*   eidx  = (const int*)d_in[1];
    const float* ea    = (const float*)d_in[2];
    const float* mask  = (const float*)d_in[3];
    const float* W1    = (const float*)d_in[4];
    const float* b1    = (const float*)d_in[5];
    const float* W2    = (const float*)d_in[6];
    const float* b2    = (const float*)d_in[7];
    const float* U1    = (const float*)d_in[8];
    const float* c1    = (const float*)d_in[9];
    const float* U2    = (const float*)d_in[10];
    const float* c2    = (const float*)d_in[11];
    const float* gamma = (const float*)d_in[12];
    const float* beta  = (const float*)d_in[13];
    float* out = (float*)d_out;
    char*  ws  = (char*)d_ws;

    float* S     = (float*)(ws + OFF_S);
    float* deg   = (float*)(ws + OFF_DEG);
    u16*   PQ    = (u16*)(ws + OFF_PQ);
    u16*   aggrb = (u16*)(ws + OFF_AGGRB);
    u16*   WpqT  = (u16*)(ws + OFF_WPQT);
    u16*   W2T   = (u16*)(ws + OFF_W2T);
    u16*   U1T   = (u16*)(ws + OFF_U1T);
    u16*   U2T   = (u16*)(ws + OFF_U2T);

    hipMemsetAsync(S, 0, (size_t)NN * H_DIM * sizeof(float), stream);
    hipMemsetAsync(deg, 0, (size_t)NN * sizeof(float), stream);

    k_prep_w<<<1536, 256, 0, stream>>>(W1, W2, U1, U2, WpqT, W2T, U1T, U2T);
    k_gemm_pq<<<(NN / 64) * 2, 256, 0, stream>>>(h, WpqT, PQ);
    k_edge<<<2048, 256, 0, stream>>>(PQ, eidx, ea, W1, b1, S, deg);
    k_gemm_s<<<NN / 64, 256, 0, stream>>>(S, W2T, deg, b2, aggrb);
    k_nodes<<<NN / 64, 256, 0, stream>>>(h, aggrb, U1T, U2T, c1, c2, gamma, beta, mask, out);
}

// Round 4
// 339.536 us; speedup vs baseline: 5.6507x; 5.6507x over previous
//
#include <hip/hip_runtime.h>

// ---------------- problem constants ----------------
#define H_DIM 256
#define E_NUM 524288
#define NN    32768          // B*N nodes
#define K2    512            // 2H
#define K2S   520            // LDS row stride (u16) kernel k_nodes
#define SAS   264            // LDS row stride (u16) for 256-wide A tiles
#define XS    264            // fp32/u16 intermediate row stride in k_nodes

typedef unsigned short u16;
typedef unsigned int   u32;
typedef __attribute__((ext_vector_type(8))) short s16x8;
typedef __attribute__((ext_vector_type(4))) float f32x4;
typedef __attribute__((ext_vector_type(4))) unsigned short u16x4;

__device__ __forceinline__ u16 f2b(float x) {
    u32 u = __float_as_uint(x);
    u32 r = (u + 0x7FFFu + ((u >> 16) & 1u)) >> 16;   // RNE; inputs finite
    return (u16)r;
}
__device__ __forceinline__ float b2f(u16 v) {
    u32 u = ((u32)v) << 16;
    return __uint_as_float(u);
}
__device__ __forceinline__ void fma4(float4& acc, float s, const float4& vw) {
    acc.x += s * vw.x; acc.y += s * vw.y; acc.z += s * vw.z; acc.w += s * vw.w;
}

// ---------------- weight prep: build bf16 transposed weights ----------------
__global__ __launch_bounds__(256) void k_prep_w(
    const float* __restrict__ W1, const float* __restrict__ W2,
    const float* __restrict__ U1, const float* __restrict__ U2,
    u16* __restrict__ WpqT, u16* __restrict__ W2T,
    u16* __restrict__ U1T, u16* __restrict__ U2T) {
    int idx = blockIdx.x * 256 + threadIdx.x;
    if (idx < 131072) {                       // WpqT
        int c = idx >> 8, k = idx & 255;
        float v = (c < 256) ? W1[k * 256 + c] : W1[(256 + k) * 256 + (c - 256)];
        WpqT[idx] = f2b(v);
    } else if (idx < 196608) {                // W2T
        int i = idx - 131072; int c = i >> 8, k = i & 255;
        W2T[i] = f2b(W2[k * 256 + c]);
    } else if (idx < 327680) {                // U1T
        int i = idx - 196608; int c = i >> 9, k = i & 511;
        U1T[i] = f2b(U1[(size_t)k * 256 + c]);
    } else if (idx < 393216) {                // U2T
        int i = idx - 327680; int c = i >> 8, k = i & 255;
        U2T[i] = f2b(U2[k * 256 + c]);
    }
}

// ---------------- CSR build ----------------
__global__ __launch_bounds__(256) void k_hist(const int* __restrict__ eidx,
                                              int* __restrict__ cnt) {
    int i = blockIdx.x * 256 + threadIdx.x;
    if (i < E_NUM) atomicAdd(&cnt[eidx[E_NUM + i]], 1);
}

__global__ __launch_bounds__(256) void k_scan(const int* __restrict__ cnt,
                                              int* __restrict__ base,
                                              int* __restrict__ nxt) {
    __shared__ int part[256];
    const int t = threadIdx.x;
    const int st = t * 128;
    int s = 0;
    for (int i = 0; i < 128; ++i) s += cnt[st + i];
    part[t] = s;
    __syncthreads();
    if (t == 0) {
        int r = 0;
        for (int i = 0; i < 256; ++i) { int v = part[i]; part[i] = r; r += v; }
        base[NN] = r;
    }
    __syncthreads();
    int off = part[t];
    for (int i = 0; i < 128; ++i) {
        int v = cnt[st + i];
        base[st + i] = off;
        nxt[st + i] = off;
        off += v;
    }
}

__global__ __launch_bounds__(256) void k_scatter(const int* __restrict__ eidx,
                                                 int* __restrict__ nxt,
                                                 int2* __restrict__ elist) {
    int i = blockIdx.x * 256 + threadIdx.x;
    if (i < E_NUM) {
        int d = eidx[E_NUM + i];
        int p = atomicAdd(&nxt[d], 1);
        elist[p] = make_int2(eidx[i], i);
    }
}

// ---------------- node GEMM: [P|Q] = h @ [W1a|W1b]  (bf16 out, NN x 512) ----------------
__global__ __launch_bounds__(256, 2) void k_gemm_pq(
    const float* __restrict__ h, const u16* __restrict__ WpqT,
    u16* __restrict__ PQ) {
    __shared__ __align__(16) u16 sA[64 * SAS];
    const int t = threadIdx.x;
    const int rowTile = blockIdx.x >> 1, q = blockIdx.x & 1;
    const int n0 = rowTile * 64;
    {   // stage h tile (fp32 -> bf16)
        const int r = t >> 2, g = t & 3;
        const float* hrow = h + (size_t)(n0 + r) * 256;
        u16* rowp = sA + r * SAS;
#pragma unroll
        for (int j = 0; j < 8; ++j) {
            const int c = g + 4 * j;
            float4 v0 = *reinterpret_cast<const float4*>(hrow + c * 8);
            float4 v1 = *reinterpret_cast<const float4*>(hrow + c * 8 + 4);
            s16x8 o;
            o[0] = (short)f2b(v0.x); o[1] = (short)f2b(v0.y);
            o[2] = (short)f2b(v0.z); o[3] = (short)f2b(v0.w);
            o[4] = (short)f2b(v1.x); o[5] = (short)f2b(v1.y);
            o[6] = (short)f2b(v1.z); o[7] = (short)f2b(v1.w);
            *reinterpret_cast<s16x8*>(rowp + c * 8) = o;
        }
    }
    __syncthreads();
    const int lane = t & 63, wv = t >> 6;
    const int l15 = lane & 15, l4 = lane >> 4;
    const int colBase = wv * 64 + l15;
    const f32x4 z4 = {0.f, 0.f, 0.f, 0.f};
    f32x4 acc[4][4];
#pragma unroll
    for (int m = 0; m < 4; ++m)
#pragma unroll
        for (int n = 0; n < 4; ++n) acc[m][n] = z4;
    {
        const u16* Bb = WpqT + (size_t)(q * 256 + colBase) * 256 + l4 * 8;
        for (int kk = 0; kk < 8; ++kk) {
            s16x8 a[4], b[4];
#pragma unroll
            for (int m = 0; m < 4; ++m)
                a[m] = *reinterpret_cast<const s16x8*>(sA + (m * 16 + l15) * SAS + kk * 32 + l4 * 8);
#pragma unroll
            for (int n = 0; n < 4; ++n)
                b[n] = *reinterpret_cast<const s16x8*>(Bb + (size_t)n * 16 * 256 + kk * 32);
#pragma unroll
            for (int m = 0; m < 4; ++m)
#pragma unroll
                for (int n = 0; n < 4; ++n)
                    acc[m][n] = __builtin_amdgcn_mfma_f32_16x16x32_bf16(a[m], b[n], acc[m][n], 0, 0, 0);
        }
    }
#pragma unroll
    for (int m = 0; m < 4; ++m)
#pragma unroll
        for (int j = 0; j < 4; ++j) {
            const int row = n0 + m * 16 + l4 * 4 + j;
            u16* op = PQ + (size_t)row * 512 + q * 256 + colBase;
#pragma unroll
            for (int n = 0; n < 4; ++n) op[n * 16] = f2b(acc[m][n][j]);
        }
}

// ---------------- aggregation: S[d] = sum_e silu(P[src]+Q[d]+ea@W1c+b1), bf16 out ----------------
// grid = NN/4 blocks x 4 waves; wave = one destination node; lane owns 4 cols.
__global__ __launch_bounds__(256, 4) void k_aggr(
    const u16* __restrict__ PQ, const int2* __restrict__ elist,
    const int* __restrict__ base, const float* __restrict__ ea,
    const float* __restrict__ W1, const float* __restrict__ b1,
    u16* __restrict__ Sb) {
    const int t = threadIdx.x, lane = t & 63, wv = t >> 6;
    const int d = blockIdx.x * 4 + wv;
    const int c0 = lane * 4;
    // W1c (rows 512..527) in registers
    float4 Wr[16];
#pragma unroll
    for (int k = 0; k < 16; ++k)
        Wr[k] = *reinterpret_cast<const float4*>(W1 + (size_t)(512 + k) * 256 + c0);
    // qb = b1 + Q[d]
    float4 qb = *reinterpret_cast<const float4*>(b1 + c0);
    {
        u16x4 qv = *reinterpret_cast<const u16x4*>(PQ + (size_t)d * 512 + 256 + c0);
        qb.x += b2f(qv.x); qb.y += b2f(qv.y); qb.z += b2f(qv.z); qb.w += b2f(qv.w);
    }
    const int e0 = base[d], e1 = base[d + 1];
    float4 acc = {0.f, 0.f, 0.f, 0.f};
    for (int cb = e0; cb < e1; cb += 64) {
        const int n = min(64, e1 - cb);
        int2 ee = make_int2(0, 0);
        if (lane < n) ee = elist[cb + lane];
        // prefetch edge 0
        int src = __shfl(ee.x, 0), eid = __shfl(ee.y, 0);
        u16x4 pv = *reinterpret_cast<const u16x4*>(PQ + (size_t)src * 512 + c0);
        const float* ep = ea + (size_t)eid * 16;
        float4 a0 = *reinterpret_cast<const float4*>(ep);
        float4 a1 = *reinterpret_cast<const float4*>(ep + 4);
        float4 a2 = *reinterpret_cast<const float4*>(ep + 8);
        float4 a3 = *reinterpret_cast<const float4*>(ep + 12);
        for (int k = 0; k < n; ++k) {
            const u16x4 pc = pv;
            const float4 e0v = a0, e1v = a1, e2v = a2, e3v = a3;
            if (k + 1 < n) {   // prefetch next edge while computing current
                src = __shfl(ee.x, k + 1); eid = __shfl(ee.y, k + 1);
                pv = *reinterpret_cast<const u16x4*>(PQ + (size_t)src * 512 + c0);
                const float* ep2 = ea + (size_t)eid * 16;
                a0 = *reinterpret_cast<const float4*>(ep2);
                a1 = *reinterpret_cast<const float4*>(ep2 + 4);
                a2 = *reinterpret_cast<const float4*>(ep2 + 8);
                a3 = *reinterpret_cast<const float4*>(ep2 + 12);
            }
            float4 x = qb;
            x.x += b2f(pc.x); x.y += b2f(pc.y); x.z += b2f(pc.z); x.w += b2f(pc.w);
            fma4(x, e0v.x, Wr[0]);  fma4(x, e0v.y, Wr[1]);
            fma4(x, e0v.z, Wr[2]);  fma4(x, e0v.w, Wr[3]);
            fma4(x, e1v.x, Wr[4]);  fma4(x, e1v.y, Wr[5]);
            fma4(x, e1v.z, Wr[6]);  fma4(x, e1v.w, Wr[7]);
            fma4(x, e2v.x, Wr[8]);  fma4(x, e2v.y, Wr[9]);
            fma4(x, e2v.z, Wr[10]); fma4(x, e2v.w, Wr[11]);
            fma4(x, e3v.x, Wr[12]); fma4(x, e3v.y, Wr[13]);
            fma4(x, e3v.z, Wr[14]); fma4(x, e3v.w, Wr[15]);
            acc.x += x.x / (1.f + __expf(-x.x));
            acc.y += x.y / (1.f + __expf(-x.y));
            acc.z += x.z / (1.f + __expf(-x.z));
            acc.w += x.w / (1.f + __expf(-x.w));
        }
    }
    u16x4 o;
    o.x = f2b(acc.x); o.y = f2b(acc.y); o.z = f2b(acc.z); o.w = f2b(acc.w);
    *reinterpret_cast<u16x4*>(Sb + (size_t)d * 256 + c0) = o;
}

// ---------------- node GEMM: aggr = S @ W2 + deg*b2  (bf16 in/out) ----------------
__global__ __launch_bounds__(256, 2) void k_gemm_s(
    const u16* __restrict__ Sb, const u16* __restrict__ W2T,
    const int* __restrict__ base, const float* __restrict__ b2,
    u16* __restrict__ aggrb) {
    __shared__ __align__(16) u16 sA[64 * SAS];
    const int t = threadIdx.x;
    const int n0 = blockIdx.x * 64;
    {   // stage S tile (bf16 copy)
        const int r = t >> 2, g = t & 3;
        const u16* srow = Sb + (size_t)(n0 + r) * 256;
        u16* rowp = sA + r * SAS;
#pragma unroll
        for (int j = 0; j < 8; ++j) {
            const int c = g + 4 * j;
            *reinterpret_cast<s16x8*>(rowp + c * 8) =
                *reinterpret_cast<const s16x8*>(srow + c * 8);
        }
    }
    __syncthreads();
    const int lane = t & 63, wv = t >> 6;
    const int l15 = lane & 15, l4 = lane >> 4;
    const int colBase = wv * 64 + l15;
    const f32x4 z4 = {0.f, 0.f, 0.f, 0.f};
    f32x4 acc[4][4];
#pragma unroll
    for (int m = 0; m < 4; ++m)
#pragma unroll
        for (int n = 0; n < 4; ++n) acc[m][n] = z4;
    {
        const u16* Bb = W2T + (size_t)colBase * 256 + l4 * 8;
        for (int kk = 0; kk < 8; ++kk) {
            s16x8 a[4], b[4];
#pragma unroll
            for (int m = 0; m < 4; ++m)
                a[m] = *reinterpret_cast<const s16x8*>(sA + (m * 16 + l15) * SAS + kk * 32 + l4 * 8);
#pragma unroll
            for (int n = 0; n < 4; ++n)
                b[n] = *reinterpret_cast<const s16x8*>(Bb + (size_t)n * 16 * 256 + kk * 32);
#pragma unroll
            for (int m = 0; m < 4; ++m)
#pragma unroll
                for (int n = 0; n < 4; ++n)
                    acc[m][n] = __builtin_amdgcn_mfma_f32_16x16x32_bf16(a[m], b[n], acc[m][n], 0, 0, 0);
        }
    }
    float b2v[4];
#pragma unroll
    for (int n = 0; n < 4; ++n) b2v[n] = b2[colBase + n * 16];
#pragma unroll
    for (int m = 0; m < 4; ++m)
#pragma unroll
        for (int j = 0; j < 4; ++j) {
            const int row = n0 + m * 16 + l4 * 4 + j;
            const float dv = (float)(base[row + 1] - base[row]);
            u16* op = aggrb + (size_t)row * 256 + colBase;
#pragma unroll
            for (int n = 0; n < 4; ++n) op[n * 16] = f2b(acc[m][n][j] + dv * b2v[n]);
        }
}

// ---------------- node update MLP + residual + LayerNorm + mask ----------------
__global__ __launch_bounds__(256, 2) void k_nodes(
    const float* __restrict__ h, const u16* __restrict__ aggrb,
    const u16* __restrict__ U1T, const u16* __restrict__ U2T,
    const float* __restrict__ c1, const float* __restrict__ c2,
    const float* __restrict__ gamma, const float* __restrict__ beta,
    const float* __restrict__ mask,
    float* __restrict__ out) {
    __shared__ __align__(16) char smemraw[64 * XS * 4];
    u16* sA = reinterpret_cast<u16*>(smemraw);           // [64][K2S] bf16
    const int t  = threadIdx.x;
    const int n0 = blockIdx.x * 64;

    {   // stage [h(bf16-converted) | aggrb]
        const int r = t >> 2, g = t & 3;
        const int node = n0 + r;
        const float* hrow = h + (size_t)node * H_DIM;
        const u16* arow = aggrb + (size_t)node * H_DIM;
        u16* rowp = sA + r * K2S;
#pragma unroll
        for (int j = 0; j < 16; ++j) {
            const int c = g + 4 * j;   // 0..63
            if (c < 32) {
                float4 v0 = *reinterpret_cast<const float4*>(hrow + c * 8);
                float4 v1 = *reinterpret_cast<const float4*>(hrow + c * 8 + 4);
                s16x8 o;
                o[0] = (short)f2b(v0.x); o[1] = (short)f2b(v0.y);
                o[2] = (short)f2b(v0.z); o[3] = (short)f2b(v0.w);
                o[4] = (short)f2b(v1.x); o[5] = (short)f2b(v1.y);
                o[6] = (short)f2b(v1.z); o[7] = (short)f2b(v1.w);
                *reinterpret_cast<s16x8*>(rowp + c * 8) = o;
            } else {
                const int cc = c - 32;
                *reinterpret_cast<s16x8*>(rowp + 256 + cc * 8) =
                    *reinterpret_cast<const s16x8*>(arow + cc * 8);
            }
        }
    }
    __syncthreads();

    const int lane = t & 63, wv = t >> 6;
    const int l15 = lane & 15, l4 = lane >> 4;
    const int colBase = wv * 64 + l15;
    const f32x4 z4 = {0.f, 0.f, 0.f, 0.f};

    f32x4 acc[4][4];
#pragma unroll
    for (int m = 0; m < 4; ++m)
#pragma unroll
        for (int n = 0; n < 4; ++n) acc[m][n] = z4;

    // ---- GEMM1b: (64 x 512) @ U1T^T ----
    {
        const u16* Bb = U1T + (size_t)colBase * K2 + l4 * 8;
        for (int kk = 0; kk < 16; ++kk) {
            s16x8 a[4], b[4];
#pragma unroll
            for (int m = 0; m < 4; ++m)
                a[m] = *reinterpret_cast<const s16x8*>(sA + (m * 16 + l15) * K2S + kk * 32 + l4 * 8);
#pragma unroll
            for (int n = 0; n < 4; ++n)
                b[n] = *reinterpret_cast<const s16x8*>(Bb + (size_t)n * 16 * K2 + kk * 32);
#pragma unroll
            for (int m = 0; m < 4; ++m)
#pragma unroll
                for (int n = 0; n < 4; ++n)
                    acc[m][n] = __builtin_amdgcn_mfma_f32_16x16x32_bf16(a[m], b[n], acc[m][n], 0, 0, 0);
        }
    }
    __syncthreads();

    // ---- epilogue 1: +c1, silu, bf16 -> sX ----
    {
        u16* sX = reinterpret_cast<u16*>(smemraw);
        float c1v[4];
#pragma unroll
        for (int n = 0; n < 4; ++n) c1v[n] = c1[colBase + n * 16];
#pragma unroll
        for (int m = 0; m < 4; ++m)
#pragma unroll
            for (int n = 0; n < 4; ++n)
#pragma unroll
                for (int j = 0; j < 4; ++j) {
                    float x = acc[m][n][j] + c1v[n];
                    float s = x / (1.f + __expf(-x));
                    sX[(m * 16 + l4 * 4 + j) * XS + colBase + n * 16] = f2b(s);
                }
    }
    __syncthreads();

    // ---- GEMM2b: (64 x 256) @ U2T^T ----
#pragma unroll
    for (int m = 0; m < 4; ++m)
#pragma unroll
        for (int n = 0; n < 4; ++n) acc[m][n] = z4;
    {
        const u16* sX = reinterpret_cast<u16*>(smemraw);
        const u16* Bb = U2T + (size_t)colBase * H_DIM + l4 * 8;
        for (int kk = 0; kk < 8; ++kk) {
            s16x8 a[4], b[4];
#pragma unroll
            for (int m = 0; m < 4; ++m)
                a[m] = *reinterpret_cast<const s16x8*>(sX + (m * 16 + l15) * XS + kk * 32 + l4 * 8);
#pragma unroll
            for (int n = 0; n < 4; ++n)
                b[n] = *reinterpret_cast<const s16x8*>(Bb + (size_t)n * 16 * H_DIM + kk * 32);
#pragma unroll
            for (int m = 0; m < 4; ++m)
#pragma unroll
                for (int n = 0; n < 4; ++n)
                    acc[m][n] = __builtin_amdgcn_mfma_f32_16x16x32_bf16(a[m], b[n], acc[m][n], 0, 0, 0);
        }
    }
    __syncthreads();   // done reading sX before overwriting as fp32

    // ---- epilogue 2: +c2 + residual -> sF (fp32) ----
    {
        float* sF = reinterpret_cast<float*>(smemraw);   // [64][XS]
        float c2v[4];
#pragma unroll
        for (int n = 0; n < 4; ++n) c2v[n] = c2[colBase + n * 16];
#pragma unroll
        for (int m = 0; m < 4; ++m)
#pragma unroll
            for (int n = 0; n < 4; ++n)
#pragma unroll
                for (int j = 0; j < 4; ++j) {
                    const int row = m * 16 + l4 * 4 + j;
                    const float hv = h[(size_t)(n0 + row) * H_DIM + colBase + n * 16];
                    sF[row * XS + colBase + n * 16] = acc[m][n][j] + c2v[n] + hv;
                }
    }
    __syncthreads();

    // ---- LayerNorm + mask + store (4 threads per row) ----
    {
        const float* sF = reinterpret_cast<const float*>(smemraw);
        const int rr = t >> 2, p = t & 3;
        const float* rowf = sF + rr * XS + p * 64;
        float s1 = 0.f, s2 = 0.f;
#pragma unroll
        for (int i = 0; i < 64; ++i) { float v = rowf[i]; s1 += v; s2 += v * v; }
        s1 += __shfl_xor(s1, 1); s1 += __shfl_xor(s1, 2);
        s2 += __shfl_xor(s2, 1); s2 += __shfl_xor(s2, 2);
        const float mu   = s1 * (1.f / 256.f);
        const float var  = s2 * (1.f / 256.f) - mu * mu;
        const float rstd = rsqrtf(var + 1e-5f);
        const int node = n0 + rr;
        const float mk = mask[node];
        float* op = out + (size_t)node * H_DIM + p * 64;
        const float* gp = gamma + p * 64;
        const float* bp = beta + p * 64;
#pragma unroll
        for (int i = 0; i < 64; i += 4) {
            float4 x  = *reinterpret_cast<const float4*>(rowf + i);
            float4 g4 = *reinterpret_cast<const float4*>(gp + i);
            float4 b4 = *reinterpret_cast<const float4*>(bp + i);
            float4 o;
            o.x = (((x.x - mu) * rstd) * g4.x + b4.x) * mk;
            o.y = (((x.y - mu) * rstd) * g4.y + b4.y) * mk;
            o.z = (((x.z - mu) * rstd) * g4.z + b4.z) * mk;
            o.w = (((x.w - mu) * rstd) * g4.w + b4.w) * mk;
            *reinterpret_cast<float4*>(op + i) = o;
        }
    }
}

// ---------------- workspace layout (bytes) ----------------
#define OFF_PQ     0ull                      // 32768*512*2 = 33554432
#define OFF_SB     33554432ull               // 32768*256*2 = 16777216
#define OFF_AGGRB  50331648ull               // 32768*256*2 = 16777216
#define OFF_WPQT   67108864ull               // 512*256*2   = 262144
#define OFF_W2T    67371008ull               // 256*256*2   = 131072
#define OFF_U1T    67502080ull               // 256*512*2   = 262144
#define OFF_U2T    67764224ull               // 256*256*2   = 131072
#define OFF_CNT    67895296ull               // 32768*4     = 131072
#define OFF_BASE   68026368ull               // (32768+1)*4 -> 131328
#define OFF_NEXT   68157696ull               // 32768*4     = 131072
#define OFF_ELIST  68288768ull               // 524288*8    = 4194304

extern "C" void kernel_launch(void* const* d_in, const int* in_sizes, int n_in,
                              void* d_out, int out_size, void* d_ws, size_t ws_size,
                              hipStream_t stream) {
    const float* h     = (const float*)d_in[0];
    const int*   eidx  = (const int*)d_in[1];
    const float* ea    = (const float*)d_in[2];
    const float* mask  = (const float*)d_in[3];
    const float* W1    = (const float*)d_in[4];
    const float* b1    = (const float*)d_in[5];
    const float* W2    = (const float*)d_in[6];
    const float* b2    = (const float*)d_in[7];
    const float* U1    = (const float*)d_in[8];
    const float* c1    = (const float*)d_in[9];
    const float* U2    = (const float*)d_in[10];
    const float* c2    = (const float*)d_in[11];
    const float* gamma = (const float*)d_in[12];
    const float* beta  = (const float*)d_in[13];
    float* out = (float*)d_out;
    char*  ws  = (char*)d_ws;

    u16*  PQ    = (u16*)(ws + OFF_PQ);
    u16*  Sb    = (u16*)(ws + OFF_SB);
    u16*  aggrb = (u16*)(ws + OFF_AGGRB);
    u16*  WpqT  = (u16*)(ws + OFF_WPQT);
    u16*  W2T   = (u16*)(ws + OFF_W2T);
    u16*  U1T   = (u16*)(ws + OFF_U1T);
    u16*  U2T   = (u16*)(ws + OFF_U2T);
    int*  cnt   = (int*)(ws + OFF_CNT);
    int*  base  = (int*)(ws + OFF_BASE);
    int*  nxt   = (int*)(ws + OFF_NEXT);
    int2* elist = (int2*)(ws + OFF_ELIST);

    hipMemsetAsync(cnt, 0, (size_t)NN * sizeof(int), stream);

    k_prep_w<<<1536, 256, 0, stream>>>(W1, W2, U1, U2, WpqT, W2T, U1T, U2T);
    k_hist<<<E_NUM / 256, 256, 0, stream>>>(eidx, cnt);
    k_scan<<<1, 256, 0, stream>>>(cnt, base, nxt);
    k_scatter<<<E_NUM / 256, 256, 0, stream>>>(eidx, nxt, elist);
    k_gemm_pq<<<(NN / 64) * 2, 256, 0, stream>>>(h, WpqT, PQ);
    k_aggr<<<NN / 4, 256, 0, stream>>>(PQ, elist, base, ea, W1, b1, Sb);
    k_gemm_s<<<NN / 64, 256, 0, stream>>>(Sb, W2T, base, b2, aggrb);
    k_nodes<<<NN / 64, 256, 0, stream>>>(h, aggrb, U1T, U2T, c1, c2, gamma, beta, mask, out);
}

// Round 5
// 326.547 us; speedup vs baseline: 5.8755x; 1.0398x over previous
//
#include <hip/hip_runtime.h>

// ---------------- problem constants ----------------
#define H_DIM 256
#define E_NUM 524288
#define NN    32768          // B*N nodes
#define K2    512            // 2H
#define K2S   520            // LDS row stride (u16) k_post A-tile
#define SAS   264            // LDS row stride (u16) for 256-wide A tiles
#define XS    264            // fp32 intermediate row stride in k_post
#define NPW   4              // dst nodes per wave in k_aggr

typedef unsigned short u16;
typedef unsigned int   u32;
typedef __attribute__((ext_vector_type(8))) short s16x8;
typedef __attribute__((ext_vector_type(4))) float f32x4;
typedef __attribute__((ext_vector_type(2))) float f32x2;
typedef __attribute__((ext_vector_type(4))) unsigned short u16x4;

__device__ __forceinline__ u16 f2b(float x) {
    u32 u = __float_as_uint(x);
    u32 r = (u + 0x7FFFu + ((u >> 16) & 1u)) >> 16;   // RNE; inputs finite
    return (u16)r;
}
__device__ __forceinline__ float b2f(u16 v) {
    u32 u = ((u32)v) << 16;
    return __uint_as_float(u);
}
__device__ __forceinline__ float fsig(float x) {       // fast sigmoid
    return __builtin_amdgcn_rcpf(1.f + __expf(-x));
}

// ---------------- weight prep: build bf16 transposed weights ----------------
__global__ __launch_bounds__(256) void k_prep_w(
    const float* __restrict__ W1, const float* __restrict__ W2,
    const float* __restrict__ U1, const float* __restrict__ U2,
    u16* __restrict__ WpqT, u16* __restrict__ W2T,
    u16* __restrict__ U1T, u16* __restrict__ U2T) {
    int idx = blockIdx.x * 256 + threadIdx.x;
    if (idx < 131072) {                       // WpqT
        int c = idx >> 8, k = idx & 255;
        float v = (c < 256) ? W1[k * 256 + c] : W1[(256 + k) * 256 + (c - 256)];
        WpqT[idx] = f2b(v);
    } else if (idx < 196608) {                // W2T
        int i = idx - 131072; int c = i >> 8, k = i & 255;
        W2T[i] = f2b(W2[k * 256 + c]);
    } else if (idx < 327680) {                // U1T
        int i = idx - 196608; int c = i >> 9, k = i & 511;
        U1T[i] = f2b(U1[(size_t)k * 256 + c]);
    } else if (idx < 393216) {                // U2T
        int i = idx - 327680; int c = i >> 8, k = i & 255;
        U2T[i] = f2b(U2[k * 256 + c]);
    }
}

// ---------------- CSR build ----------------
__global__ __launch_bounds__(256) void k_hist(const int* __restrict__ eidx,
                                              int* __restrict__ cnt) {
    int i = blockIdx.x * 256 + threadIdx.x;
    if (i < E_NUM) atomicAdd(&cnt[eidx[E_NUM + i]], 1);
}

__global__ __launch_bounds__(256) void k_scan(const int* __restrict__ cnt,
                                              int* __restrict__ base,
                                              int* __restrict__ nxt) {
    __shared__ int part[256];
    const int t = threadIdx.x;
    const int st = t * 128;
    int s = 0;
    for (int i = 0; i < 128; ++i) s += cnt[st + i];
    part[t] = s;
    __syncthreads();
    if (t == 0) {
        int r = 0;
        for (int i = 0; i < 256; ++i) { int v = part[i]; part[i] = r; r += v; }
        base[NN] = r;
    }
    __syncthreads();
    int off = part[t];
    for (int i = 0; i < 128; ++i) {
        int v = cnt[st + i];
        base[st + i] = off;
        nxt[st + i] = off;
        off += v;
    }
}

__global__ __launch_bounds__(256) void k_scatter(const int* __restrict__ eidx,
                                                 int* __restrict__ nxt,
                                                 int2* __restrict__ elist) {
    int i = blockIdx.x * 256 + threadIdx.x;
    if (i < E_NUM) {
        int d = eidx[E_NUM + i];
        int p = atomicAdd(&nxt[d], 1);
        elist[p] = make_int2(eidx[i], i);
    }
}

// ---------------- node GEMM: [P|Q] = h @ [W1a|W1b]  (bf16 out, NN x 512) ----------------
__global__ __launch_bounds__(256, 2) void k_gemm_pq(
    const float* __restrict__ h, const u16* __restrict__ WpqT,
    u16* __restrict__ PQ) {
    __shared__ __align__(16) u16 sA[64 * SAS];
    const int t = threadIdx.x;
    const int rowTile = blockIdx.x >> 1, q = blockIdx.x & 1;
    const int n0 = rowTile * 64;
    {   // stage h tile (fp32 -> bf16)
        const int r = t >> 2, g = t & 3;
        const float* hrow = h + (size_t)(n0 + r) * 256;
        u16* rowp = sA + r * SAS;
#pragma unroll
        for (int j = 0; j < 8; ++j) {
            const int c = g + 4 * j;
            float4 v0 = *reinterpret_cast<const float4*>(hrow + c * 8);
            float4 v1 = *reinterpret_cast<const float4*>(hrow + c * 8 + 4);
            s16x8 o;
            o[0] = (short)f2b(v0.x); o[1] = (short)f2b(v0.y);
            o[2] = (short)f2b(v0.z); o[3] = (short)f2b(v0.w);
            o[4] = (short)f2b(v1.x); o[5] = (short)f2b(v1.y);
            o[6] = (short)f2b(v1.z); o[7] = (short)f2b(v1.w);
            *reinterpret_cast<s16x8*>(rowp + c * 8) = o;
        }
    }
    __syncthreads();
    const int lane = t & 63, wv = t >> 6;
    const int l15 = lane & 15, l4 = lane >> 4;
    const int colBase = wv * 64 + l15;
    const f32x4 z4 = {0.f, 0.f, 0.f, 0.f};
    f32x4 acc[4][4];
#pragma unroll
    for (int m = 0; m < 4; ++m)
#pragma unroll
        for (int n = 0; n < 4; ++n) acc[m][n] = z4;
    {
        const u16* Bb = WpqT + (size_t)(q * 256 + colBase) * 256 + l4 * 8;
        for (int kk = 0; kk < 8; ++kk) {
            s16x8 a[4], b[4];
#pragma unroll
            for (int m = 0; m < 4; ++m)
                a[m] = *reinterpret_cast<const s16x8*>(sA + (m * 16 + l15) * SAS + kk * 32 + l4 * 8);
#pragma unroll
            for (int n = 0; n < 4; ++n)
                b[n] = *reinterpret_cast<const s16x8*>(Bb + (size_t)n * 16 * 256 + kk * 32);
#pragma unroll
            for (int m = 0; m < 4; ++m)
#pragma unroll
                for (int n = 0; n < 4; ++n)
                    acc[m][n] = __builtin_amdgcn_mfma_f32_16x16x32_bf16(a[m], b[n], acc[m][n], 0, 0, 0);
        }
    }
#pragma unroll
    for (int m = 0; m < 4; ++m)
#pragma unroll
        for (int j = 0; j < 4; ++j) {
            const int row = n0 + m * 16 + l4 * 4 + j;
            u16* op = PQ + (size_t)row * 512 + q * 256 + colBase;
#pragma unroll
            for (int n = 0; n < 4; ++n) op[n * 16] = f2b(acc[m][n][j]);
        }
}

// ---------------- aggregation: S[d] = sum_e silu(P[src]+Q[d]+ea@W1c+b1), bf16 out ----------------
// grid = NN/(4*NPW) blocks x 4 waves; wave = NPW dst nodes; lane owns 4 cols.
__global__ __launch_bounds__(256, 4) void k_aggr(
    const u16* __restrict__ PQ, const int2* __restrict__ elist,
    const int* __restrict__ base, const float* __restrict__ ea,
    const float* __restrict__ W1, const float* __restrict__ b1,
    u16* __restrict__ Sb) {
    const int t = threadIdx.x, lane = t & 63, wv = t >> 6;
    const int c0 = lane * 4;
    // W1c (rows 512..527) in registers as f32x2 pairs (targets v_pk_fma_f32)
    f32x2 WrL[16], WrH[16];
#pragma unroll
    for (int k = 0; k < 16; ++k) {
        float4 w = *reinterpret_cast<const float4*>(W1 + (size_t)(512 + k) * 256 + c0);
        WrL[k] = f32x2{w.x, w.y};
        WrH[k] = f32x2{w.z, w.w};
    }
    const float4 b1v = *reinterpret_cast<const float4*>(b1 + c0);

    const int dBase = (blockIdx.x * 4 + wv) * NPW;
    for (int nn = 0; nn < NPW; ++nn) {
        const int d = dBase + nn;
        // qb = b1 + Q[d]
        f32x2 qbL = {b1v.x, b1v.y}, qbH = {b1v.z, b1v.w};
        {
            u16x4 qv = *reinterpret_cast<const u16x4*>(PQ + (size_t)d * 512 + 256 + c0);
            qbL[0] += b2f(qv.x); qbL[1] += b2f(qv.y);
            qbH[0] += b2f(qv.z); qbH[1] += b2f(qv.w);
        }
        const int e0 = base[d], e1 = base[d + 1];
        f32x2 accL = {0.f, 0.f}, accH = {0.f, 0.f};
        for (int cb = e0; cb < e1; cb += 64) {
            const int n = min(64, e1 - cb);
            int2 ee = make_int2(0, 0);
            if (lane < n) ee = elist[cb + lane];
            // prefetch edge 0
            int src = __shfl(ee.x, 0), eid = __shfl(ee.y, 0);
            u16x4 pv = *reinterpret_cast<const u16x4*>(PQ + (size_t)src * 512 + c0);
            const float* ep = ea + (size_t)eid * 16;
            float4 a0 = *reinterpret_cast<const float4*>(ep);
            float4 a1 = *reinterpret_cast<const float4*>(ep + 4);
            float4 a2 = *reinterpret_cast<const float4*>(ep + 8);
            float4 a3 = *reinterpret_cast<const float4*>(ep + 12);
            for (int k = 0; k < n; ++k) {
                const u16x4 pc = pv;
                const float4 e0v = a0, e1v = a1, e2v = a2, e3v = a3;
                if (k + 1 < n) {   // prefetch next edge while computing current
                    src = __shfl(ee.x, k + 1); eid = __shfl(ee.y, k + 1);
                    pv = *reinterpret_cast<const u16x4*>(PQ + (size_t)src * 512 + c0);
                    const float* ep2 = ea + (size_t)eid * 16;
                    a0 = *reinterpret_cast<const float4*>(ep2);
                    a1 = *reinterpret_cast<const float4*>(ep2 + 4);
                    a2 = *reinterpret_cast<const float4*>(ep2 + 8);
                    a3 = *reinterpret_cast<const float4*>(ep2 + 12);
                }
                f32x2 xL = qbL, xH = qbH;
                xL[0] += b2f(pc.x); xL[1] += b2f(pc.y);
                xH[0] += b2f(pc.z); xH[1] += b2f(pc.w);
                xL = xL + WrL[0]  * e0v.x; xH = xH + WrH[0]  * e0v.x;
                xL = xL + WrL[1]  * e0v.y; xH = xH + WrH[1]  * e0v.y;
                xL = xL + WrL[2]  * e0v.z; xH = xH + WrH[2]  * e0v.z;
                xL = xL + WrL[3]  * e0v.w; xH = xH + WrH[3]  * e0v.w;
                xL = xL + WrL[4]  * e1v.x; xH = xH + WrH[4]  * e1v.x;
                xL = xL + WrL[5]  * e1v.y; xH = xH + WrH[5]  * e1v.y;
                xL = xL + WrL[6]  * e1v.z; xH = xH + WrH[6]  * e1v.z;
                xL = xL + WrL[7]  * e1v.w; xH = xH + WrH[7]  * e1v.w;
                xL = xL + WrL[8]  * e2v.x; xH = xH + WrH[8]  * e2v.x;
                xL = xL + WrL[9]  * e2v.y; xH = xH + WrH[9]  * e2v.y;
                xL = xL + WrL[10] * e2v.z; xH = xH + WrH[10] * e2v.z;
                xL = xL + WrL[11] * e2v.w; xH = xH + WrH[11] * e2v.w;
                xL = xL + WrL[12] * e3v.x; xH = xH + WrH[12] * e3v.x;
                xL = xL + WrL[13] * e3v.y; xH = xH + WrH[13] * e3v.y;
                xL = xL + WrL[14] * e3v.z; xH = xH + WrH[14] * e3v.z;
                xL = xL + WrL[15] * e3v.w; xH = xH + WrH[15] * e3v.w;
                // fast silu: x * sigmoid(x)
                accL[0] += xL[0] * fsig(xL[0]);
                accL[1] += xL[1] * fsig(xL[1]);
                accH[0] += xH[0] * fsig(xH[0]);
                accH[1] += xH[1] * fsig(xH[1]);
            }
        }
        u16x4 o;
        o.x = f2b(accL[0]); o.y = f2b(accL[1]);
        o.z = f2b(accH[0]); o.w = f2b(accH[1]);
        *reinterpret_cast<u16x4*>(Sb + (size_t)d * 256 + c0) = o;
    }
}

// ---------------- fused: aggr GEMM (Sb@W2 + deg*b2) + update MLP + residual + LN + mask ----------------
__global__ __launch_bounds__(256, 2) void k_post(
    const float* __restrict__ h, const u16* __restrict__ Sb,
    const u16* __restrict__ W2T, const int* __restrict__ base,
    const float* __restrict__ b2,
    const u16* __restrict__ U1T, const u16* __restrict__ U2T,
    const float* __restrict__ c1, const float* __restrict__ c2,
    const float* __restrict__ gamma, const float* __restrict__ beta,
    const float* __restrict__ mask,
    float* __restrict__ out) {
    __shared__ __align__(16) char smemraw[64 * XS * 4];  // 67584 B, multi-purpose
    u16* sA = reinterpret_cast<u16*>(smemraw);           // [64][K2S] bf16
    const int t  = threadIdx.x;
    const int n0 = blockIdx.x * 64;

    {   // stage [h(bf16) | Sb] -> sA
        const int r = t >> 2, g = t & 3;
        const int node = n0 + r;
        const float* hrow = h + (size_t)node * H_DIM;
        const u16* srow = Sb + (size_t)node * H_DIM;
        u16* rowp = sA + r * K2S;
#pragma unroll
        for (int j = 0; j < 16; ++j) {
            const int c = g + 4 * j;   // 0..63
            if (c < 32) {
                float4 v0 = *reinterpret_cast<const float4*>(hrow + c * 8);
                float4 v1 = *reinterpret_cast<const float4*>(hrow + c * 8 + 4);
                s16x8 o;
                o[0] = (short)f2b(v0.x); o[1] = (short)f2b(v0.y);
                o[2] = (short)f2b(v0.z); o[3] = (short)f2b(v0.w);
                o[4] = (short)f2b(v1.x); o[5] = (short)f2b(v1.y);
                o[6] = (short)f2b(v1.z); o[7] = (short)f2b(v1.w);
                *reinterpret_cast<s16x8*>(rowp + c * 8) = o;
            } else {
                const int cc = c - 32;
                *reinterpret_cast<s16x8*>(rowp + 256 + cc * 8) =
                    *reinterpret_cast<const s16x8*>(srow + cc * 8);
            }
        }
    }
    __syncthreads();

    const int lane = t & 63, wv = t >> 6;
    const int l15 = lane & 15, l4 = lane >> 4;
    const int colBase = wv * 64 + l15;
    const f32x4 z4 = {0.f, 0.f, 0.f, 0.f};

    f32x4 acc[4][4];
#pragma unroll
    for (int m = 0; m < 4; ++m)
#pragma unroll
        for (int n = 0; n < 4; ++n) acc[m][n] = z4;

    // ---- GEMM-S: aggr = Sb @ W2 (A from sA[256..511], K=256) ----
    {
        const u16* Bb = W2T + (size_t)colBase * 256 + l4 * 8;
        for (int kk = 0; kk < 8; ++kk) {
            s16x8 a[4], b[4];
#pragma unroll
            for (int m = 0; m < 4; ++m)
                a[m] = *reinterpret_cast<const s16x8*>(sA + (m * 16 + l15) * K2S + 256 + kk * 32 + l4 * 8);
#pragma unroll
            for (int n = 0; n < 4; ++n)
                b[n] = *reinterpret_cast<const s16x8*>(Bb + (size_t)n * 16 * 256 + kk * 32);
#pragma unroll
            for (int m = 0; m < 4; ++m)
#pragma unroll
                for (int n = 0; n < 4; ++n)
                    acc[m][n] = __builtin_amdgcn_mfma_f32_16x16x32_bf16(a[m], b[n], acc[m][n], 0, 0, 0);
        }
    }
    __syncthreads();   // everyone done reading Sb half

    // ---- write aggr (+deg*b2) bf16 back into sA[256..511] ----
    {
        float b2v[4];
#pragma unroll
        for (int n = 0; n < 4; ++n) b2v[n] = b2[colBase + n * 16];
#pragma unroll
        for (int m = 0; m < 4; ++m)
#pragma unroll
            for (int j = 0; j < 4; ++j) {
                const int row = m * 16 + l4 * 4 + j;
                const float dv = (float)(base[n0 + row + 1] - base[n0 + row]);
#pragma unroll
                for (int n = 0; n < 4; ++n)
                    sA[row * K2S + 256 + colBase + n * 16] = f2b(acc[m][n][j] + dv * b2v[n]);
            }
    }
    __syncthreads();

    // ---- GEMM1b: (64 x 512) @ U1T^T ----
#pragma unroll
    for (int m = 0; m < 4; ++m)
#pragma unroll
        for (int n = 0; n < 4; ++n) acc[m][n] = z4;
    {
        const u16* Bb = U1T + (size_t)colBase * K2 + l4 * 8;
        for (int kk = 0; kk < 16; ++kk) {
            s16x8 a[4], b[4];
#pragma unroll
            for (int m = 0; m < 4; ++m)
                a[m] = *reinterpret_cast<const s16x8*>(sA + (m * 16 + l15) * K2S + kk * 32 + l4 * 8);
#pragma unroll
            for (int n = 0; n < 4; ++n)
                b[n] = *reinterpret_cast<const s16x8*>(Bb + (size_t)n * 16 * K2 + kk * 32);
#pragma unroll
            for (int m = 0; m < 4; ++m)
#pragma unroll
                for (int n = 0; n < 4; ++n)
                    acc[m][n] = __builtin_amdgcn_mfma_f32_16x16x32_bf16(a[m], b[n], acc[m][n], 0, 0, 0);
        }
    }
    __syncthreads();

    // ---- epilogue 1: +c1, silu, bf16 -> sX ----
    {
        u16* sX = reinterpret_cast<u16*>(smemraw);
        float c1v[4];
#pragma unroll
        for (int n = 0; n < 4; ++n) c1v[n] = c1[colBase + n * 16];
#pragma unroll
        for (int m = 0; m < 4; ++m)
#pragma unroll
            for (int n = 0; n < 4; ++n)
#pragma unroll
                for (int j = 0; j < 4; ++j) {
                    float x = acc[m][n][j] + c1v[n];
                    float s = x * fsig(x);
                    sX[(m * 16 + l4 * 4 + j) * XS + colBase + n * 16] = f2b(s);
                }
    }
    __syncthreads();

    // ---- GEMM2b: (64 x 256) @ U2T^T ----
#pragma unroll
    for (int m = 0; m < 4; ++m)
#pragma unroll
        for (int n = 0; n < 4; ++n) acc[m][n] = z4;
    {
        const u16* sX = reinterpret_cast<u16*>(smemraw);
        const u16* Bb = U2T + (size_t)colBase * H_DIM + l4 * 8;
        for (int kk = 0; kk < 8; ++kk) {
            s16x8 a[4], b[4];
#pragma unroll
            for (int m = 0; m < 4; ++m)
                a[m] = *reinterpret_cast<const s16x8*>(sX + (m * 16 + l15) * XS + kk * 32 + l4 * 8);
#pragma unroll
            for (int n = 0; n < 4; ++n)
                b[n] = *reinterpret_cast<const s16x8*>(Bb + (size_t)n * 16 * H_DIM + kk * 32);
#pragma unroll
            for (int m = 0; m < 4; ++m)
#pragma unroll
                for (int n = 0; n < 4; ++n)
                    acc[m][n] = __builtin_amdgcn_mfma_f32_16x16x32_bf16(a[m], b[n], acc[m][n], 0, 0, 0);
        }
    }
    __syncthreads();   // done reading sX before overwriting as fp32

    // ---- epilogue 2: +c2 + residual -> sF (fp32) ----
    {
        float* sF = reinterpret_cast<float*>(smemraw);   // [64][XS]
        float c2v[4];
#pragma unroll
        for (int n = 0; n < 4; ++n) c2v[n] = c2[colBase + n * 16];
#pragma unroll
        for (int m = 0; m < 4; ++m)
#pragma unroll
            for (int n = 0; n < 4; ++n)
#pragma unroll
                for (int j = 0; j < 4; ++j) {
                    const int row = m * 16 + l4 * 4 + j;
                    const float hv = h[(size_t)(n0 + row) * H_DIM + colBase + n * 16];
                    sF[row * XS + colBase + n * 16] = acc[m][n][j] + c2v[n] + hv;
                }
    }
    __syncthreads();

    // ---- LayerNorm + mask + store (4 threads per row) ----
    {
        const float* sF = reinterpret_cast<const float*>(smemraw);
        const int rr = t >> 2, p = t & 3;
        const float* rowf = sF + rr * XS + p * 64;
        float s1 = 0.f, s2 = 0.f;
#pragma unroll
        for (int i = 0; i < 64; ++i) { float v = rowf[i]; s1 += v; s2 += v * v; }
        s1 += __shfl_xor(s1, 1); s1 += __shfl_xor(s1, 2);
        s2 += __shfl_xor(s2, 1); s2 += __shfl_xor(s2, 2);
        const float mu   = s1 * (1.f / 256.f);
        const float var  = s2 * (1.f / 256.f) - mu * mu;
        const float rstd = rsqrtf(var + 1e-5f);
        const int node = n0 + rr;
        const float mk = mask[node];
        float* op = out + (size_t)node * H_DIM + p * 64;
        const float* gp = gamma + p * 64;
        const float* bp = beta + p * 64;
#pragma unroll
        for (int i = 0; i < 64; i += 4) {
            float4 x  = *reinterpret_cast<const float4*>(rowf + i);
            float4 g4 = *reinterpret_cast<const float4*>(gp + i);
            float4 b4 = *reinterpret_cast<const float4*>(bp + i);
            float4 o;
            o.x = (((x.x - mu) * rstd) * g4.x + b4.x) * mk;
            o.y = (((x.y - mu) * rstd) * g4.y + b4.y) * mk;
            o.z = (((x.z - mu) * rstd) * g4.z + b4.z) * mk;
            o.w = (((x.w - mu) * rstd) * g4.w + b4.w) * mk;
            *reinterpret_cast<float4*>(op + i) = o;
        }
    }
}

// ---------------- workspace layout (bytes) ----------------
#define OFF_PQ     0ull                      // 32768*512*2 = 33554432
#define OFF_SB     33554432ull               // 32768*256*2 = 16777216
#define OFF_WPQT   50331648ull               // 512*256*2   = 262144
#define OFF_W2T    50593792ull               // 256*256*2   = 131072
#define OFF_U1T    50724864ull               // 256*512*2   = 262144
#define OFF_U2T    50987008ull               // 256*256*2   = 131072
#define OFF_CNT    51118080ull               // 32768*4     = 131072
#define OFF_BASE   51249152ull               // (32768+1)*4 -> 131328
#define OFF_NEXT   51380480ull               // 32768*4     = 131072
#define OFF_ELIST  51511552ull               // 524288*8    = 4194304

extern "C" void kernel_launch(void* const* d_in, const int* in_sizes, int n_in,
                              void* d_out, int out_size, void* d_ws, size_t ws_size,
                              hipStream_t stream) {
    const float* h     = (const float*)d_in[0];
    const int*   eidx  = (const int*)d_in[1];
    const float* ea    = (const float*)d_in[2];
    const float* mask  = (const float*)d_in[3];
    const float* W1    = (const float*)d_in[4];
    const float* b1    = (const float*)d_in[5];
    const float* W2    = (const float*)d_in[6];
    const float* b2    = (const float*)d_in[7];
    const float* U1    = (const float*)d_in[8];
    const float* c1    = (const float*)d_in[9];
    const float* U2    = (const float*)d_in[10];
    const float* c2    = (const float*)d_in[11];
    const float* gamma = (const float*)d_in[12];
    const float* beta  = (const float*)d_in[13];
    float* out = (float*)d_out;
    char*  ws  = (char*)d_ws;

    u16*  PQ    = (u16*)(ws + OFF_PQ);
    u16*  Sb    = (u16*)(ws + OFF_SB);
    u16*  WpqT  = (u16*)(ws + OFF_WPQT);
    u16*  W2T   = (u16*)(ws + OFF_W2T);
    u16*  U1T   = (u16*)(ws + OFF_U1T);
    u16*  U2T   = (u16*)(ws + OFF_U2T);
    int*  cnt   = (int*)(ws + OFF_CNT);
    int*  base  = (int*)(ws + OFF_BASE);
    int*  nxt   = (int*)(ws + OFF_NEXT);
    int2* elist = (int2*)(ws + OFF_ELIST);

    hipMemsetAsync(cnt, 0, (size_t)NN * sizeof(int), stream);

    k_prep_w<<<1536, 256, 0, stream>>>(W1, W2, U1, U2, WpqT, W2T, U1T, U2T);
    k_hist<<<E_NUM / 256, 256, 0, stream>>>(eidx, cnt);
    k_scan<<<1, 256, 0, stream>>>(cnt, base, nxt);
    k_scatter<<<E_NUM / 256, 256, 0, stream>>>(eidx, nxt, elist);
    k_gemm_pq<<<(NN / 64) * 2, 256, 0, stream>>>(h, WpqT, PQ);
    k_aggr<<<NN / (4 * NPW), 256, 0, stream>>>(PQ, elist, base, ea, W1, b1, Sb);
    k_post<<<NN / 64, 256, 0, stream>>>(h, Sb, W2T, base, b2, U1T, U2T,
                                        c1, c2, gamma, beta, mask, out);
}